// Round 6
// baseline (1300.945 us; speedup 1.0000x reference)
//
#include <hip/hip_runtime.h>

// GIN on MI355X. Round 20 = R19 with the compile fix (nontemporal builtins
// need a native ext_vector float2, not HIP_vector_type float2).
// Launch-isolated L2-window gather for k_agg:
//  - Node-ID space split into 4 windows of 25000 (3.2MB of y each: fits a
//    4MB XCD L2 replicated on all 8 XCDs). k_agg -> 4 launches/layer
//    (k_agg_win<PASS>); pass r gathers ONLY neighbors in window r.
//  - Out-of-window neighbors: address cndmask'd to the window base row
//    (hot) and value cndmask'd to 0 -> full 8-deep load pipelining.
//  - Cross-pass partials: fp32 N*64 buffer, NONTEMPORAL ld/st. Pass 3 adds
//    self row + bias, relu, writes bf16 u. Same fp32 summation, reordered.
//  - build / MFMA MLPs / pool / readout byte-identical to R14/R18 base.

constexpr int N   = 100000;
constexpr int E   = 1600000;
constexpr int DIN = 128;
constexpr int H   = 64;
constexpr int OUT = 16;
constexpr int G   = 512;
constexpr int SLOT = 64;
constexpr int WIN  = 25000;   // nodes per window (4 windows x 3.2MB of y)

constexpr int NB_EDGES    = (E + 255) / 256;       // 6250
constexpr int NB_TILE64   = (N + 63) / 64;         // 1563
constexpr int NB_BUILD    = NB_TILE64 + NB_EDGES;  // 7813
constexpr int NB_WAVENODE = (N * 64 + 255) / 256;  // 25000

typedef __attribute__((ext_vector_type(8))) short bf16x8;
typedef __attribute__((ext_vector_type(4))) float f32x4;
typedef __attribute__((ext_vector_type(2))) float f32x2;

__device__ __forceinline__ float bf2f(unsigned short u) {
  union { unsigned int i; float f; } v;
  v.i = ((unsigned int)u) << 16;
  return v.f;
}
__device__ __forceinline__ unsigned int f2bf(float f) {
  union { float f; unsigned int i; } v;
  v.f = f;
  unsigned int r = v.i + 0x7fff + ((v.i >> 16) & 1);  // RNE
  return r >> 16;
}

// ---- weight prep: wt[mat][n*64+k] = bf16(w[mat][k*64+n]), 9 mats 64x64. ----
__global__ void k_prep(const float* __restrict__ w2_0, const float* __restrict__ w2_r,
                       const float* __restrict__ w1_r, unsigned short* __restrict__ wt) {
  int i = blockIdx.x * 256 + threadIdx.x;
  if (i >= 9 * 4096) return;
  int mat = i >> 12, rem = i & 4095;
  int n = rem >> 6, k = rem & 63;
  const float* s;
  if (mat == 0) s = w2_0;
  else if (mat < 5) s = w2_r + (mat - 1) * 4096;
  else s = w1_r + (mat - 5) * 4096;
  wt[i] = (unsigned short)f2bf(s[k * 64 + n]);
}

// ---- fused build: interleaved roles. blockIdx%5==0 -> gemm tile. ----
__global__ __launch_bounds__(256, 4) void k_build_gemm(const int* __restrict__ src,
                                                       const int* __restrict__ dst,
                                                       int* __restrict__ deg,
                                                       int* __restrict__ slots,
                                                       const float* __restrict__ x,
                                                       const float* __restrict__ w1,
                                                       unsigned short* __restrict__ y) {
  __shared__ unsigned int sx[64 * 65];
  int t = threadIdx.x;
  int b = blockIdx.x;
  int q5 = b / 5;
  if (b - q5 * 5 != 0) {
    int e = (b - q5 - 1) * 256 + t;
    if (e < E) {
      int s = src[e];
      int d = dst[e];
      int p = atomicAdd(&deg[d], 1);
      if (p < SLOT) __builtin_nontemporal_store(s, &slots[(size_t)d * SLOT + p]);
    }
    return;
  }
  int nb = q5 * 64;
  int rows = min(64, N - nb);
#pragma unroll
  for (int it = 0; it < 8; ++it) {
    int idx4 = it * 256 + t;
    int r = idx4 >> 5, d4 = idx4 & 31;
    if (r < rows) {
      float4 v = ((const float4*)(x + (size_t)(nb + r) * DIN))[d4];
      sx[r * 65 + d4 * 2]     = f2bf(v.x) | (f2bf(v.y) << 16);
      sx[r * 65 + d4 * 2 + 1] = f2bf(v.z) | (f2bf(v.w) << 16);
    }
  }
  __syncthreads();
  int l = t & 63;
  int jg = __builtin_amdgcn_readfirstlane(t >> 6);
  float acc[16];
#pragma unroll
  for (int j = 0; j < 16; ++j) acc[j] = 0.f;
#pragma unroll 2
  for (int dd = 0; dd < 64; ++dd) {
    unsigned int pv = sx[l * 65 + dd];
    float vlo = bf2f((unsigned short)(pv & 0xffff));
    float vhi = bf2f((unsigned short)(pv >> 16));
    const float* wr0 = w1 + (2 * dd) * H + jg * 16;
    const float* wr1 = wr0 + H;
#pragma unroll
    for (int j = 0; j < 16; ++j) acc[j] += vlo * wr0[j] + vhi * wr1[j];
  }
  __syncthreads();
  unsigned int* so = sx;
#pragma unroll
  for (int k = 0; k < 8; ++k)
    so[l * 33 + jg * 8 + k] = f2bf(acc[2 * k]) | (f2bf(acc[2 * k + 1]) << 16);
  __syncthreads();
  unsigned int* yo = (unsigned int*)y;
#pragma unroll
  for (int it = 0; it < 8; ++it) {
    int m = it * 256 + t;
    int r = m >> 5, c = m & 31;
    if (r < rows) yo[(size_t)(nb + r) * 32 + c] = so[r * 33 + c];
  }
}

// ---- windowed aggregation pass PASS in [0,4):
//      gathers only neighbors with id in [PASS*WIN, PASS*WIN+WIN);
//      out-of-window: load window base row (hot), value cndmask'd to 0.
//      Partials accumulate in part[] (fp32, nontemporal). Pass 3 adds
//      self row + bias, relu, writes bf16 u. ----
template <int PASS>
__global__ void k_agg_win(const unsigned short* __restrict__ y,
                          const int* __restrict__ deg,
                          const int* __restrict__ slots,
                          const float* __restrict__ b1,
                          float* __restrict__ part,
                          unsigned short* __restrict__ u) {
  constexpr int LO = PASS * WIN;
  constexpr int HI = LO + WIN;
  int w = (blockIdx.x * 256 + threadIdx.x) >> 6;
  int lane = threadIdx.x & 63;
  if (w >= N) return;
  int half = lane >> 5, fl = lane & 31;
  const unsigned int* y32 = (const unsigned int*)y;
  const int* srow = slots + (size_t)w * SLOT;
  int d = min(deg[w], SLOT);
  int dp = d >> 1;  // neighbor pairs; position 2i+half belongs to this half
  float ax0 = 0.f, ay0 = 0.f, ax1 = 0.f, ay1 = 0.f;
  float ax2 = 0.f, ay2 = 0.f, ax3 = 0.f, ay3 = 0.f;
  float ax4 = 0.f, ay4 = 0.f, ax5 = 0.f, ay5 = 0.f;
  float ax6 = 0.f, ay6 = 0.f, ax7 = 0.f, ay7 = 0.f;
  auto gacc = [&](int c, float& ax, float& ay) {
    bool in = (c >= LO) && (c < HI);
    int ca = in ? c : LO;
    unsigned int g = y32[(size_t)ca * 32 + fl];
    g = in ? g : 0u;
    ax += bf2f((unsigned short)(g & 0xffff));
    ay += bf2f((unsigned short)(g >> 16));
  };
  int i = 0;
  for (; i + 8 <= dp; i += 8) {
    int c0 = srow[2 * (i + 0) + half], c1 = srow[2 * (i + 1) + half];
    int c2 = srow[2 * (i + 2) + half], c3 = srow[2 * (i + 3) + half];
    int c4 = srow[2 * (i + 4) + half], c5 = srow[2 * (i + 5) + half];
    int c6 = srow[2 * (i + 6) + half], c7 = srow[2 * (i + 7) + half];
    gacc(c0, ax0, ay0); gacc(c1, ax1, ay1);
    gacc(c2, ax2, ay2); gacc(c3, ax3, ay3);
    gacc(c4, ax4, ay4); gacc(c5, ax5, ay5);
    gacc(c6, ax6, ay6); gacc(c7, ax7, ay7);
  }
  if (dp & 4) {
    int c0 = srow[2 * (i + 0) + half], c1 = srow[2 * (i + 1) + half];
    int c2 = srow[2 * (i + 2) + half], c3 = srow[2 * (i + 3) + half];
    gacc(c0, ax0, ay0); gacc(c1, ax1, ay1);
    gacc(c2, ax2, ay2); gacc(c3, ax3, ay3);
    i += 4;
  }
  if (dp & 2) {
    int c0 = srow[2 * (i + 0) + half], c1 = srow[2 * (i + 1) + half];
    gacc(c0, ax4, ay4); gacc(c1, ax5, ay5);
    i += 2;
  }
  if (dp & 1) {
    int c0 = srow[2 * i + half];
    gacc(c0, ax6, ay6);
  }
  if (d & 1) {  // last odd neighbor: half 0 only
    int c0 = srow[d - 1];
    if (half == 0) gacc(c0, ax7, ay7);
  }
  float sxv = ((ax0 + ax1) + (ax2 + ax3)) + ((ax4 + ax5) + (ax6 + ax7));
  float syv = ((ay0 + ay1) + (ay2 + ay3)) + ((ay4 + ay5) + (ay6 + ay7));
  sxv += __shfl_xor(sxv, 32);
  syv += __shfl_xor(syv, 32);
  if (half == 0) {
    f32x2* pp = ((f32x2*)part) + ((size_t)w * 32 + fl);
    if (PASS == 0) {
      f32x2 o; o.x = sxv; o.y = syv;
      __builtin_nontemporal_store(o, pp);
    } else if (PASS < 3) {
      f32x2 o = __builtin_nontemporal_load(pp);
      o.x += sxv; o.y += syv;
      __builtin_nontemporal_store(o, pp);
    } else {
      f32x2 o = __builtin_nontemporal_load(pp);
      unsigned int sv = y32[(size_t)w * 32 + fl];  // self row
      float rx = o.x + sxv + bf2f((unsigned short)(sv & 0xffff)) + b1[2 * fl];
      float ry = o.y + syv + bf2f((unsigned short)(sv >> 16)) + b1[2 * fl + 1];
      rx = fmaxf(rx, 0.f);
      ry = fmaxf(ry, 0.f);
      ((unsigned int*)u)[(size_t)w * 32 + fl] = f2bf(rx) | (f2bf(ry) << 16);
    }
  }
}

// ---- MFMA fused: Y = (relu(U @ W2 + b2)) @ W1n. ----
__global__ __launch_bounds__(256, 4) void k_fused(const unsigned int* __restrict__ u32,
                                                  const unsigned short* __restrict__ w2t,
                                                  const float* __restrict__ b2,
                                                  const unsigned short* __restrict__ w1t,
                                                  unsigned short* __restrict__ yout) {
  __shared__ unsigned short sU[64 * 72];
  __shared__ unsigned short sH[64 * 72];
  int t = threadIdx.x;
  int nb = blockIdx.x * 64;
  int rows = min(64, N - nb);
  unsigned int* sU32 = (unsigned int*)sU;
#pragma unroll
  for (int it = 0; it < 8; ++it) {
    int m = it * 256 + t;
    int r = m >> 5, c = m & 31;
    if (r < rows) sU32[r * 36 + c] = u32[(size_t)(nb + r) * 32 + c];
  }
  __syncthreads();
  int lane = t & 63;
  int w = __builtin_amdgcn_readfirstlane(t >> 6);
  int sub = lane & 15, quad = lane >> 4;
  f32x4 acc[4];
#pragma unroll
  for (int nt = 0; nt < 4; ++nt) {
    float bv = b2[nt * 16 + sub];
    acc[nt].x = bv; acc[nt].y = bv; acc[nt].z = bv; acc[nt].w = bv;
  }
#pragma unroll
  for (int ks = 0; ks < 2; ++ks) {
    bf16x8 a = *(const bf16x8*)&sU[(w * 16 + sub) * 72 + ks * 32 + quad * 8];
#pragma unroll
    for (int nt = 0; nt < 4; ++nt) {
      bf16x8 bb = *(const bf16x8*)&w2t[(nt * 16 + sub) * 64 + ks * 32 + quad * 8];
      acc[nt] = __builtin_amdgcn_mfma_f32_16x16x32_bf16(a, bb, acc[nt], 0, 0, 0);
    }
  }
#pragma unroll
  for (int nt = 0; nt < 4; ++nt) {
    sH[(w * 16 + quad * 4 + 0) * 72 + nt * 16 + sub] = (unsigned short)f2bf(fmaxf(acc[nt].x, 0.f));
    sH[(w * 16 + quad * 4 + 1) * 72 + nt * 16 + sub] = (unsigned short)f2bf(fmaxf(acc[nt].y, 0.f));
    sH[(w * 16 + quad * 4 + 2) * 72 + nt * 16 + sub] = (unsigned short)f2bf(fmaxf(acc[nt].z, 0.f));
    sH[(w * 16 + quad * 4 + 3) * 72 + nt * 16 + sub] = (unsigned short)f2bf(fmaxf(acc[nt].w, 0.f));
  }
  f32x4 acc2[4];
#pragma unroll
  for (int nt = 0; nt < 4; ++nt) { acc2[nt].x = 0.f; acc2[nt].y = 0.f; acc2[nt].z = 0.f; acc2[nt].w = 0.f; }
#pragma unroll
  for (int ks = 0; ks < 2; ++ks) {
    bf16x8 a = *(const bf16x8*)&sH[(w * 16 + sub) * 72 + ks * 32 + quad * 8];
#pragma unroll
    for (int nt = 0; nt < 4; ++nt) {
      bf16x8 bb = *(const bf16x8*)&w1t[(nt * 16 + sub) * 64 + ks * 32 + quad * 8];
      acc2[nt] = __builtin_amdgcn_mfma_f32_16x16x32_bf16(a, bb, acc2[nt], 0, 0, 0);
    }
  }
#pragma unroll
  for (int nt = 0; nt < 4; ++nt) {
    sU[(w * 16 + quad * 4 + 0) * 72 + nt * 16 + sub] = (unsigned short)f2bf(acc2[nt].x);
    sU[(w * 16 + quad * 4 + 1) * 72 + nt * 16 + sub] = (unsigned short)f2bf(acc2[nt].y);
    sU[(w * 16 + quad * 4 + 2) * 72 + nt * 16 + sub] = (unsigned short)f2bf(acc2[nt].z);
    sU[(w * 16 + quad * 4 + 3) * 72 + nt * 16 + sub] = (unsigned short)f2bf(acc2[nt].w);
  }
  __syncthreads();
  unsigned int* yo = (unsigned int*)yout;
#pragma unroll
  for (int it = 0; it < 8; ++it) {
    int m = it * 256 + t;
    int r = m >> 5, c = m & 31;
    if (r < rows) yo[(size_t)(nb + r) * 32 + c] = sU32[r * 36 + c];
  }
}

// ---- layer 4: H5 = relu(U @ W2 + b2) via MFMA + segment-reduce pool ----
__global__ __launch_bounds__(256, 4) void k_last_pool(const unsigned int* __restrict__ u32,
                                                      const unsigned short* __restrict__ w2t,
                                                      const float* __restrict__ b2,
                                                      const int* __restrict__ batch,
                                                      float* __restrict__ g) {
  __shared__ unsigned short sU[64 * 72];
  __shared__ float sb[64 * 65];
  __shared__ int sbatch[64];
  int t = threadIdx.x;
  int nb = blockIdx.x * 64;
  int rows = min(64, N - nb);
  unsigned int* sU32 = (unsigned int*)sU;
#pragma unroll
  for (int it = 0; it < 8; ++it) {
    int m = it * 256 + t;
    int r = m >> 5, c = m & 31;
    if (r < rows) sU32[r * 36 + c] = u32[(size_t)(nb + r) * 32 + c];
  }
  if (t < 64) sbatch[t] = batch[min(nb + t, N - 1)];
  __syncthreads();
  int lane = t & 63;
  int w = __builtin_amdgcn_readfirstlane(t >> 6);
  int sub = lane & 15, quad = lane >> 4;
  f32x4 acc[4];
#pragma unroll
  for (int nt = 0; nt < 4; ++nt) {
    float bv = b2[nt * 16 + sub];
    acc[nt].x = bv; acc[nt].y = bv; acc[nt].z = bv; acc[nt].w = bv;
  }
#pragma unroll
  for (int ks = 0; ks < 2; ++ks) {
    bf16x8 a = *(const bf16x8*)&sU[(w * 16 + sub) * 72 + ks * 32 + quad * 8];
#pragma unroll
    for (int nt = 0; nt < 4; ++nt) {
      bf16x8 bb = *(const bf16x8*)&w2t[(nt * 16 + sub) * 64 + ks * 32 + quad * 8];
      acc[nt] = __builtin_amdgcn_mfma_f32_16x16x32_bf16(a, bb, acc[nt], 0, 0, 0);
    }
  }
#pragma unroll
  for (int nt = 0; nt < 4; ++nt) {
    sb[(w * 16 + quad * 4 + 0) * 65 + nt * 16 + sub] = fmaxf(acc[nt].x, 0.f);
    sb[(w * 16 + quad * 4 + 1) * 65 + nt * 16 + sub] = fmaxf(acc[nt].y, 0.f);
    sb[(w * 16 + quad * 4 + 2) * 65 + nt * 16 + sub] = fmaxf(acc[nt].z, 0.f);
    sb[(w * 16 + quad * 4 + 3) * 65 + nt * 16 + sub] = fmaxf(acc[nt].w, 0.f);
  }
  __syncthreads();
  int d = t & 63;
  int q = t >> 6;
  int r0 = q * 16;
  int bprev = sbatch[r0];
  float acc1 = 0.f;
#pragma unroll 4
  for (int r = 0; r < 16; ++r) {
    int row = r0 + r;
    if (row >= rows) break;
    int b = sbatch[row];
    if (b != bprev) {
      __hip_atomic_fetch_add(&g[(size_t)bprev * H + d], acc1,
                             __ATOMIC_RELAXED, __HIP_MEMORY_SCOPE_AGENT);
      acc1 = 0.f;
      bprev = b;
    }
    acc1 += sb[row * 65 + d];
  }
  if (r0 < rows)
    __hip_atomic_fetch_add(&g[(size_t)bprev * H + d], acc1,
                           __ATOMIC_RELAXED, __HIP_MEMORY_SCOPE_AGENT);
}

// out[n] = relu(g[n] @ mw1 + mb1) @ mw2 + mb2
__global__ void k_readout(const float* __restrict__ g, const float* __restrict__ mw1,
                          const float* __restrict__ mb1, const float* __restrict__ mw2,
                          const float* __restrict__ mb2, float* __restrict__ out) {
  int n = blockIdx.x * 64 + threadIdx.x;
  if (n >= G) return;
  float acc[H];
#pragma unroll
  for (int j = 0; j < H; ++j) acc[j] = mb1[j];
  const float* gr = g + (size_t)n * H;
  for (int d = 0; d < H; ++d) {
    float gd = gr[d];
    const float* wr = mw1 + d * H;
#pragma unroll
    for (int j = 0; j < H; ++j) acc[j] += gd * wr[j];
  }
#pragma unroll
  for (int j = 0; j < H; ++j) acc[j] = fmaxf(acc[j], 0.f);
  float o[OUT];
#pragma unroll
  for (int tt = 0; tt < OUT; ++tt) o[tt] = mb2[tt];
  for (int d = 0; d < H; ++d) {
    float hd = acc[d];
    const float* wr = mw2 + d * OUT;
#pragma unroll
    for (int tt = 0; tt < OUT; ++tt) o[tt] += hd * wr[tt];
  }
#pragma unroll
  for (int tt = 0; tt < OUT; ++tt) out[(size_t)n * OUT + tt] = o[tt];
}

extern "C" void kernel_launch(void* const* d_in, const int* in_sizes, int n_in,
                              void* d_out, int out_size, void* d_ws, size_t ws_size,
                              hipStream_t stream) {
  const float* x     = (const float*)d_in[0];
  const int*   ei    = (const int*)d_in[1];
  const int*   batch = (const int*)d_in[2];
  const float* w1_0  = (const float*)d_in[3];
  const float* b1_0  = (const float*)d_in[4];
  const float* w2_0  = (const float*)d_in[5];
  const float* b2_0  = (const float*)d_in[6];
  const float* w1_r  = (const float*)d_in[7];
  const float* b1_r  = (const float*)d_in[8];
  const float* w2_r  = (const float*)d_in[9];
  const float* b2_r  = (const float*)d_in[10];
  const float* mw1   = (const float*)d_in[11];
  const float* mb1   = (const float*)d_in[12];
  const float* mw2   = (const float*)d_in[13];
  const float* mb2   = (const float*)d_in[14];
  float* out = (float*)d_out;

  const int* src = ei;
  const int* dst = ei + E;

  char* ws = (char*)d_ws;
  size_t off = 0;
  auto alloc = [&](size_t bytes) -> void* {
    void* p = ws + off;
    off = (off + bytes + 255) & ~(size_t)255;
    return p;
  };
  unsigned short* ybuf = (unsigned short*)alloc((size_t)N * H * 2);
  unsigned short* ubuf = (unsigned short*)alloc((size_t)N * H * 2);
  int* deg    = (int*)alloc((size_t)N * 4);
  int* slots  = (int*)alloc((size_t)N * SLOT * 4);
  float* part = (float*)alloc((size_t)N * H * 4);
  float* gbuf = (float*)alloc((size_t)G * H * 4);
  unsigned short* wt = (unsigned short*)alloc((size_t)9 * 4096 * 2);

  hipMemsetAsync(deg, 0, (size_t)N * 4, stream);
  hipMemsetAsync(gbuf, 0, (size_t)G * H * 4, stream);

  k_prep<<<144, 256, 0, stream>>>(w2_0, w2_r, w1_r, wt);
  k_build_gemm<<<NB_BUILD, 256, 0, stream>>>(src, dst, deg, slots, x, w1_0, ybuf);

  unsigned short* w2t0 = wt;
  unsigned short* w2tr = wt + 4096;
  unsigned short* w1tr = wt + 5 * 4096;

  auto agg = [&](const unsigned short* yin, const float* b1p,
                 unsigned short* uout) {
    k_agg_win<0><<<NB_WAVENODE, 256, 0, stream>>>(yin, deg, slots, b1p, part, uout);
    k_agg_win<1><<<NB_WAVENODE, 256, 0, stream>>>(yin, deg, slots, b1p, part, uout);
    k_agg_win<2><<<NB_WAVENODE, 256, 0, stream>>>(yin, deg, slots, b1p, part, uout);
    k_agg_win<3><<<NB_WAVENODE, 256, 0, stream>>>(yin, deg, slots, b1p, part, uout);
  };

  agg(ybuf, b1_0, ubuf);
  k_fused<<<NB_TILE64, 256, 0, stream>>>((const unsigned int*)ubuf, w2t0, b2_0,
                                         w1tr, ybuf);
  for (int i = 0; i < 3; ++i) {
    agg(ybuf, b1_r + i * H, ubuf);
    k_fused<<<NB_TILE64, 256, 0, stream>>>((const unsigned int*)ubuf,
                                           w2tr + i * 4096, b2_r + i * H,
                                           w1tr + (i + 1) * 4096, ybuf);
  }

  agg(ybuf, b1_r + 3 * H, ubuf);
  k_last_pool<<<NB_TILE64, 256, 0, stream>>>((const unsigned int*)ubuf,
                                             w2tr + 3 * 4096, b2_r + 3 * H,
                                             batch, gbuf);

  k_readout<<<8, 64, 0, stream>>>(gbuf, mw1, mb1, mw2, mb2, out);
}

// Round 8
// 619.406 us; speedup vs baseline: 2.1003x; 2.1003x over previous
//
#include <hip/hip_runtime.h>

// GIN on MI355X. Round 22 = R21 resubmit (R21 hit GPU-acquisition timeout,
// never ran) with one bug fixed: removed the raw s_barrier inside the
// wid<4 branch (split-barrier hazard: HW barrier counts arrivals, so 4
// waves at a mid-barrier + 4 at the final barrier release early -> race).
// It was also unnecessary: wave w writes and reads the SAME sH 16-row
// slice (within-wave LDS RAW, compiler-ordered via lgkmcnt) - exactly the
// proven k_fused structure.
// Fusion rationale (R15/R16/R18/R20): random y-gather is bound by a flat
// ~2.5-2.8 TB/s random-line service rate; hide the MLP + u round-trip
// under it. k_agg_mlp: 512-thr block = 64-node tile; 8 waves gather 8
// nodes each into LDS; barrier; waves 0-3 run the double-MFMA; all write
// yout. Ping-pong y/u buffers (no WAR race). k_agg_pool fuses layer 4.

constexpr int N   = 100000;
constexpr int E   = 1600000;
constexpr int DIN = 128;
constexpr int H   = 64;
constexpr int OUT = 16;
constexpr int G   = 512;
constexpr int SLOT = 64;

constexpr int NB_EDGES    = (E + 255) / 256;       // 6250
constexpr int NB_TILE64   = (N + 63) / 64;         // 1563
constexpr int NB_BUILD    = NB_TILE64 + NB_EDGES;  // 7813

typedef __attribute__((ext_vector_type(8))) short bf16x8;
typedef __attribute__((ext_vector_type(4))) float f32x4;

__device__ __forceinline__ float bf2f(unsigned short u) {
  union { unsigned int i; float f; } v;
  v.i = ((unsigned int)u) << 16;
  return v.f;
}
__device__ __forceinline__ unsigned int f2bf(float f) {
  union { float f; unsigned int i; } v;
  v.f = f;
  unsigned int r = v.i + 0x7fff + ((v.i >> 16) & 1);  // RNE
  return r >> 16;
}

// ---- weight prep: wt[mat][n*64+k] = bf16(w[mat][k*64+n]), 9 mats 64x64. ----
__global__ void k_prep(const float* __restrict__ w2_0, const float* __restrict__ w2_r,
                       const float* __restrict__ w1_r, unsigned short* __restrict__ wt) {
  int i = blockIdx.x * 256 + threadIdx.x;
  if (i >= 9 * 4096) return;
  int mat = i >> 12, rem = i & 4095;
  int n = rem >> 6, k = rem & 63;
  const float* s;
  if (mat == 0) s = w2_0;
  else if (mat < 5) s = w2_r + (mat - 1) * 4096;
  else s = w1_r + (mat - 5) * 4096;
  wt[i] = (unsigned short)f2bf(s[k * 64 + n]);
}

// ---- fused build: interleaved roles. blockIdx%5==0 -> gemm tile. ----
__global__ __launch_bounds__(256, 4) void k_build_gemm(const int* __restrict__ src,
                                                       const int* __restrict__ dst,
                                                       int* __restrict__ deg,
                                                       int* __restrict__ slots,
                                                       const float* __restrict__ x,
                                                       const float* __restrict__ w1,
                                                       unsigned short* __restrict__ y) {
  __shared__ unsigned int sx[64 * 65];
  int t = threadIdx.x;
  int b = blockIdx.x;
  int q5 = b / 5;
  if (b - q5 * 5 != 0) {
    int e = (b - q5 - 1) * 256 + t;
    if (e < E) {
      int s = src[e];
      int d = dst[e];
      int p = atomicAdd(&deg[d], 1);
      if (p < SLOT) __builtin_nontemporal_store(s, &slots[(size_t)d * SLOT + p]);
    }
    return;
  }
  int nb = q5 * 64;
  int rows = min(64, N - nb);
#pragma unroll
  for (int it = 0; it < 8; ++it) {
    int idx4 = it * 256 + t;
    int r = idx4 >> 5, d4 = idx4 & 31;
    if (r < rows) {
      float4 v = ((const float4*)(x + (size_t)(nb + r) * DIN))[d4];
      sx[r * 65 + d4 * 2]     = f2bf(v.x) | (f2bf(v.y) << 16);
      sx[r * 65 + d4 * 2 + 1] = f2bf(v.z) | (f2bf(v.w) << 16);
    }
  }
  __syncthreads();
  int l = t & 63;
  int jg = __builtin_amdgcn_readfirstlane(t >> 6);
  float acc[16];
#pragma unroll
  for (int j = 0; j < 16; ++j) acc[j] = 0.f;
#pragma unroll 2
  for (int dd = 0; dd < 64; ++dd) {
    unsigned int pv = sx[l * 65 + dd];
    float vlo = bf2f((unsigned short)(pv & 0xffff));
    float vhi = bf2f((unsigned short)(pv >> 16));
    const float* wr0 = w1 + (2 * dd) * H + jg * 16;
    const float* wr1 = wr0 + H;
#pragma unroll
    for (int j = 0; j < 16; ++j) acc[j] += vlo * wr0[j] + vhi * wr1[j];
  }
  __syncthreads();
  unsigned int* so = sx;
#pragma unroll
  for (int k = 0; k < 8; ++k)
    so[l * 33 + jg * 8 + k] = f2bf(acc[2 * k]) | (f2bf(acc[2 * k + 1]) << 16);
  __syncthreads();
  unsigned int* yo = (unsigned int*)y;
#pragma unroll
  for (int it = 0; it < 8; ++it) {
    int m = it * 256 + t;
    int r = m >> 5, c = m & 31;
    if (r < rows) yo[(size_t)(nb + r) * 32 + c] = so[r * 33 + c];
  }
}

// ---- per-node gather into LDS tile (R14 body, result -> sU32[r*36+fl]).
//      Wave-level: half = lane>>5 (even/odd neighbor stream), fl = lane&31. ----
__device__ __forceinline__ void gather_node(const unsigned int* __restrict__ y32,
                                            const int* __restrict__ deg,
                                            const int* __restrict__ slots,
                                            const float* __restrict__ b1,
                                            unsigned int* __restrict__ sU32,
                                            int w, int r, int half, int fl) {
  const int* srow = slots + (size_t)w * SLOT;
  int d = min(deg[w], SLOT);
  int dp = d >> 1;
  float ax0 = 0.f, ay0 = 0.f, ax1 = 0.f, ay1 = 0.f;
  float ax2 = 0.f, ay2 = 0.f, ax3 = 0.f, ay3 = 0.f;
  float ax4 = 0.f, ay4 = 0.f, ax5 = 0.f, ay5 = 0.f;
  float ax6 = 0.f, ay6 = 0.f, ax7 = 0.f, ay7 = 0.f;
  unsigned int sv = y32[(size_t)w * 32 + fl];
  if (half == 0) {
    ax0 += bf2f((unsigned short)(sv & 0xffff));
    ay0 += bf2f((unsigned short)(sv >> 16));
  }
  int i = 0;
  for (; i + 8 <= dp; i += 8) {
    int c0 = srow[2 * (i + 0) + half], c1 = srow[2 * (i + 1) + half];
    int c2 = srow[2 * (i + 2) + half], c3 = srow[2 * (i + 3) + half];
    int c4 = srow[2 * (i + 4) + half], c5 = srow[2 * (i + 5) + half];
    int c6 = srow[2 * (i + 6) + half], c7 = srow[2 * (i + 7) + half];
    unsigned int g0 = y32[(size_t)c0 * 32 + fl];
    unsigned int g1 = y32[(size_t)c1 * 32 + fl];
    unsigned int g2 = y32[(size_t)c2 * 32 + fl];
    unsigned int g3 = y32[(size_t)c3 * 32 + fl];
    unsigned int g4 = y32[(size_t)c4 * 32 + fl];
    unsigned int g5 = y32[(size_t)c5 * 32 + fl];
    unsigned int g6 = y32[(size_t)c6 * 32 + fl];
    unsigned int g7 = y32[(size_t)c7 * 32 + fl];
    ax0 += bf2f((unsigned short)(g0 & 0xffff)); ay0 += bf2f((unsigned short)(g0 >> 16));
    ax1 += bf2f((unsigned short)(g1 & 0xffff)); ay1 += bf2f((unsigned short)(g1 >> 16));
    ax2 += bf2f((unsigned short)(g2 & 0xffff)); ay2 += bf2f((unsigned short)(g2 >> 16));
    ax3 += bf2f((unsigned short)(g3 & 0xffff)); ay3 += bf2f((unsigned short)(g3 >> 16));
    ax4 += bf2f((unsigned short)(g4 & 0xffff)); ay4 += bf2f((unsigned short)(g4 >> 16));
    ax5 += bf2f((unsigned short)(g5 & 0xffff)); ay5 += bf2f((unsigned short)(g5 >> 16));
    ax6 += bf2f((unsigned short)(g6 & 0xffff)); ay6 += bf2f((unsigned short)(g6 >> 16));
    ax7 += bf2f((unsigned short)(g7 & 0xffff)); ay7 += bf2f((unsigned short)(g7 >> 16));
  }
  if (dp & 4) {
    int c0 = srow[2 * (i + 0) + half], c1 = srow[2 * (i + 1) + half];
    int c2 = srow[2 * (i + 2) + half], c3 = srow[2 * (i + 3) + half];
    unsigned int g0 = y32[(size_t)c0 * 32 + fl];
    unsigned int g1 = y32[(size_t)c1 * 32 + fl];
    unsigned int g2 = y32[(size_t)c2 * 32 + fl];
    unsigned int g3 = y32[(size_t)c3 * 32 + fl];
    ax0 += bf2f((unsigned short)(g0 & 0xffff)); ay0 += bf2f((unsigned short)(g0 >> 16));
    ax1 += bf2f((unsigned short)(g1 & 0xffff)); ay1 += bf2f((unsigned short)(g1 >> 16));
    ax2 += bf2f((unsigned short)(g2 & 0xffff)); ay2 += bf2f((unsigned short)(g2 >> 16));
    ax3 += bf2f((unsigned short)(g3 & 0xffff)); ay3 += bf2f((unsigned short)(g3 >> 16));
    i += 4;
  }
  if (dp & 2) {
    int c0 = srow[2 * (i + 0) + half], c1 = srow[2 * (i + 1) + half];
    unsigned int g0 = y32[(size_t)c0 * 32 + fl];
    unsigned int g1 = y32[(size_t)c1 * 32 + fl];
    ax4 += bf2f((unsigned short)(g0 & 0xffff)); ay4 += bf2f((unsigned short)(g0 >> 16));
    ax5 += bf2f((unsigned short)(g1 & 0xffff)); ay5 += bf2f((unsigned short)(g1 >> 16));
    i += 2;
  }
  if (dp & 1) {
    int c0 = srow[2 * i + half];
    unsigned int g0 = y32[(size_t)c0 * 32 + fl];
    ax6 += bf2f((unsigned short)(g0 & 0xffff)); ay6 += bf2f((unsigned short)(g0 >> 16));
  }
  if (d & 1) {
    int c0 = srow[d - 1];
    if (half == 0) {
      unsigned int g0 = y32[(size_t)c0 * 32 + fl];
      ax7 += bf2f((unsigned short)(g0 & 0xffff)); ay7 += bf2f((unsigned short)(g0 >> 16));
    }
  }
  float sxv = ((ax0 + ax1) + (ax2 + ax3)) + ((ax4 + ax5) + (ax6 + ax7));
  float syv = ((ay0 + ay1) + (ay2 + ay3)) + ((ay4 + ay5) + (ay6 + ay7));
  sxv += __shfl_xor(sxv, 32);
  syv += __shfl_xor(syv, 32);
  if (half == 0) {
    float rx = fmaxf(sxv + b1[2 * fl], 0.f);
    float ry = fmaxf(syv + b1[2 * fl + 1], 0.f);
    sU32[r * 36 + fl] = f2bf(rx) | (f2bf(ry) << 16);
  }
}

// ---- fused layer: gather tile -> LDS, then Y = (relu(U@W2+b2))@W1n. ----
__global__ __launch_bounds__(512) void k_agg_mlp(const unsigned short* __restrict__ y,
                                                 const int* __restrict__ deg,
                                                 const int* __restrict__ slots,
                                                 const float* __restrict__ b1,
                                                 const unsigned short* __restrict__ w2t,
                                                 const float* __restrict__ b2,
                                                 const unsigned short* __restrict__ w1t,
                                                 unsigned short* __restrict__ yout) {
  __shared__ unsigned short sU[64 * 72];
  __shared__ unsigned short sH[64 * 72];
  int t = threadIdx.x;
  int nb = blockIdx.x * 64;
  int rows = min(64, N - nb);
  int wid = t >> 6;      // 0..7
  int lane = t & 63;
  int half = lane >> 5, fl = lane & 31;
  const unsigned int* y32 = (const unsigned int*)y;
  unsigned int* sU32 = (unsigned int*)sU;
  // gather phase: wave wid handles rows wid*8 .. wid*8+7
#pragma unroll 1
  for (int k = 0; k < 8; ++k) {
    int r = wid * 8 + k;
    if (r >= rows) break;
    gather_node(y32, deg, slots, b1, sU32, nb + r, r, half, fl);
  }
  __syncthreads();
  // MFMA phase: waves 0..3. Wave w writes and reads the SAME sH 16-row
  // slice (within-wave LDS RAW, lgkmcnt-ordered) - no barrier needed,
  // same as the proven k_fused.
  if (wid < 4) {
    int w = __builtin_amdgcn_readfirstlane(wid);
    int sub = lane & 15, quad = lane >> 4;
    f32x4 acc[4];
#pragma unroll
    for (int nt = 0; nt < 4; ++nt) {
      float bv = b2[nt * 16 + sub];
      acc[nt].x = bv; acc[nt].y = bv; acc[nt].z = bv; acc[nt].w = bv;
    }
#pragma unroll
    for (int ks = 0; ks < 2; ++ks) {
      bf16x8 a = *(const bf16x8*)&sU[(w * 16 + sub) * 72 + ks * 32 + quad * 8];
#pragma unroll
      for (int nt = 0; nt < 4; ++nt) {
        bf16x8 bb = *(const bf16x8*)&w2t[(nt * 16 + sub) * 64 + ks * 32 + quad * 8];
        acc[nt] = __builtin_amdgcn_mfma_f32_16x16x32_bf16(a, bb, acc[nt], 0, 0, 0);
      }
    }
#pragma unroll
    for (int nt = 0; nt < 4; ++nt) {
      sH[(w * 16 + quad * 4 + 0) * 72 + nt * 16 + sub] = (unsigned short)f2bf(fmaxf(acc[nt].x, 0.f));
      sH[(w * 16 + quad * 4 + 1) * 72 + nt * 16 + sub] = (unsigned short)f2bf(fmaxf(acc[nt].y, 0.f));
      sH[(w * 16 + quad * 4 + 2) * 72 + nt * 16 + sub] = (unsigned short)f2bf(fmaxf(acc[nt].z, 0.f));
      sH[(w * 16 + quad * 4 + 3) * 72 + nt * 16 + sub] = (unsigned short)f2bf(fmaxf(acc[nt].w, 0.f));
    }
    f32x4 acc2[4];
#pragma unroll
    for (int nt = 0; nt < 4; ++nt) { acc2[nt].x = 0.f; acc2[nt].y = 0.f; acc2[nt].z = 0.f; acc2[nt].w = 0.f; }
#pragma unroll
    for (int ks = 0; ks < 2; ++ks) {
      bf16x8 a = *(const bf16x8*)&sH[(w * 16 + sub) * 72 + ks * 32 + quad * 8];
#pragma unroll
      for (int nt = 0; nt < 4; ++nt) {
        bf16x8 bb = *(const bf16x8*)&w1t[(nt * 16 + sub) * 64 + ks * 32 + quad * 8];
        acc2[nt] = __builtin_amdgcn_mfma_f32_16x16x32_bf16(a, bb, acc2[nt], 0, 0, 0);
      }
    }
#pragma unroll
    for (int nt = 0; nt < 4; ++nt) {
      sU[(w * 16 + quad * 4 + 0) * 72 + nt * 16 + sub] = (unsigned short)f2bf(acc2[nt].x);
      sU[(w * 16 + quad * 4 + 1) * 72 + nt * 16 + sub] = (unsigned short)f2bf(acc2[nt].y);
      sU[(w * 16 + quad * 4 + 2) * 72 + nt * 16 + sub] = (unsigned short)f2bf(acc2[nt].z);
      sU[(w * 16 + quad * 4 + 3) * 72 + nt * 16 + sub] = (unsigned short)f2bf(acc2[nt].w);
    }
  }
  __syncthreads();
  unsigned int* yo = (unsigned int*)yout;
#pragma unroll
  for (int it = 0; it < 4; ++it) {
    int m = it * 512 + t;
    int r = m >> 5, c = m & 31;
    if (r < rows) yo[(size_t)(nb + r) * 32 + c] = sU32[r * 36 + c];
  }
}

// ---- fused last layer: gather tile -> MFMA(w2)+relu -> segment pool ----
__global__ __launch_bounds__(512) void k_agg_pool(const unsigned short* __restrict__ y,
                                                  const int* __restrict__ deg,
                                                  const int* __restrict__ slots,
                                                  const float* __restrict__ b1,
                                                  const unsigned short* __restrict__ w2t,
                                                  const float* __restrict__ b2,
                                                  const int* __restrict__ batch,
                                                  float* __restrict__ g) {
  __shared__ unsigned short sU[64 * 72];
  __shared__ float sb[64 * 65];
  __shared__ int sbatch[64];
  int t = threadIdx.x;
  int nb = blockIdx.x * 64;
  int rows = min(64, N - nb);
  int wid = t >> 6;
  int lane = t & 63;
  int half = lane >> 5, fl = lane & 31;
  const unsigned int* y32 = (const unsigned int*)y;
  unsigned int* sU32 = (unsigned int*)sU;
  if (t < 64) sbatch[t] = batch[min(nb + t, N - 1)];
#pragma unroll 1
  for (int k = 0; k < 8; ++k) {
    int r = wid * 8 + k;
    if (r >= rows) break;
    gather_node(y32, deg, slots, b1, sU32, nb + r, r, half, fl);
  }
  __syncthreads();
  if (wid < 4) {
    int w = __builtin_amdgcn_readfirstlane(wid);
    int sub = lane & 15, quad = lane >> 4;
    f32x4 acc[4];
#pragma unroll
    for (int nt = 0; nt < 4; ++nt) {
      float bv = b2[nt * 16 + sub];
      acc[nt].x = bv; acc[nt].y = bv; acc[nt].z = bv; acc[nt].w = bv;
    }
#pragma unroll
    for (int ks = 0; ks < 2; ++ks) {
      bf16x8 a = *(const bf16x8*)&sU[(w * 16 + sub) * 72 + ks * 32 + quad * 8];
#pragma unroll
      for (int nt = 0; nt < 4; ++nt) {
        bf16x8 bb = *(const bf16x8*)&w2t[(nt * 16 + sub) * 64 + ks * 32 + quad * 8];
        acc[nt] = __builtin_amdgcn_mfma_f32_16x16x32_bf16(a, bb, acc[nt], 0, 0, 0);
      }
    }
#pragma unroll
    for (int nt = 0; nt < 4; ++nt) {
      sb[(w * 16 + quad * 4 + 0) * 65 + nt * 16 + sub] = fmaxf(acc[nt].x, 0.f);
      sb[(w * 16 + quad * 4 + 1) * 65 + nt * 16 + sub] = fmaxf(acc[nt].y, 0.f);
      sb[(w * 16 + quad * 4 + 2) * 65 + nt * 16 + sub] = fmaxf(acc[nt].z, 0.f);
      sb[(w * 16 + quad * 4 + 3) * 65 + nt * 16 + sub] = fmaxf(acc[nt].w, 0.f);
    }
  }
  __syncthreads();
  // pool: 8 groups x 8 rows (batch is sorted)
  int d = t & 63;
  int q = t >> 6;
  int r0 = q * 8;
  if (r0 < rows) {
    int bprev = sbatch[r0];
    float acc1 = 0.f;
#pragma unroll 4
    for (int r = 0; r < 8; ++r) {
      int row = r0 + r;
      if (row >= rows) break;
      int b = sbatch[row];
      if (b != bprev) {
        __hip_atomic_fetch_add(&g[(size_t)bprev * H + d], acc1,
                               __ATOMIC_RELAXED, __HIP_MEMORY_SCOPE_AGENT);
        acc1 = 0.f;
        bprev = b;
      }
      acc1 += sb[row * 65 + d];
    }
    __hip_atomic_fetch_add(&g[(size_t)bprev * H + d], acc1,
                           __ATOMIC_RELAXED, __HIP_MEMORY_SCOPE_AGENT);
  }
}

// out[n] = relu(g[n] @ mw1 + mb1) @ mw2 + mb2
__global__ void k_readout(const float* __restrict__ g, const float* __restrict__ mw1,
                          const float* __restrict__ mb1, const float* __restrict__ mw2,
                          const float* __restrict__ mb2, float* __restrict__ out) {
  int n = blockIdx.x * 64 + threadIdx.x;
  if (n >= G) return;
  float acc[H];
#pragma unroll
  for (int j = 0; j < H; ++j) acc[j] = mb1[j];
  const float* gr = g + (size_t)n * H;
  for (int d = 0; d < H; ++d) {
    float gd = gr[d];
    const float* wr = mw1 + d * H;
#pragma unroll
    for (int j = 0; j < H; ++j) acc[j] += gd * wr[j];
  }
#pragma unroll
  for (int j = 0; j < H; ++j) acc[j] = fmaxf(acc[j], 0.f);
  float o[OUT];
#pragma unroll
  for (int tt = 0; tt < OUT; ++tt) o[tt] = mb2[tt];
  for (int d = 0; d < H; ++d) {
    float hd = acc[d];
    const float* wr = mw2 + d * OUT;
#pragma unroll
    for (int tt = 0; tt < OUT; ++tt) o[tt] += hd * wr[tt];
  }
#pragma unroll
  for (int tt = 0; tt < OUT; ++tt) out[(size_t)n * OUT + tt] = o[tt];
}

extern "C" void kernel_launch(void* const* d_in, const int* in_sizes, int n_in,
                              void* d_out, int out_size, void* d_ws, size_t ws_size,
                              hipStream_t stream) {
  const float* x     = (const float*)d_in[0];
  const int*   ei    = (const int*)d_in[1];
  const int*   batch = (const int*)d_in[2];
  const float* w1_0  = (const float*)d_in[3];
  const float* b1_0  = (const float*)d_in[4];
  const float* w2_0  = (const float*)d_in[5];
  const float* b2_0  = (const float*)d_in[6];
  const float* w1_r  = (const float*)d_in[7];
  const float* b1_r  = (const float*)d_in[8];
  const float* w2_r  = (const float*)d_in[9];
  const float* b2_r  = (const float*)d_in[10];
  const float* mw1   = (const float*)d_in[11];
  const float* mb1   = (const float*)d_in[12];
  const float* mw2   = (const float*)d_in[13];
  const float* mb2   = (const float*)d_in[14];
  float* out = (float*)d_out;

  const int* src = ei;
  const int* dst = ei + E;

  char* ws = (char*)d_ws;
  size_t off = 0;
  auto alloc = [&](size_t bytes) -> void* {
    void* p = ws + off;
    off = (off + bytes + 255) & ~(size_t)255;
    return p;
  };
  unsigned short* ybuf = (unsigned short*)alloc((size_t)N * H * 2);
  unsigned short* ubuf = (unsigned short*)alloc((size_t)N * H * 2);
  int* deg    = (int*)alloc((size_t)N * 4);
  int* slots  = (int*)alloc((size_t)N * SLOT * 4);
  float* gbuf = (float*)alloc((size_t)G * H * 4);
  unsigned short* wt = (unsigned short*)alloc((size_t)9 * 4096 * 2);

  hipMemsetAsync(deg, 0, (size_t)N * 4, stream);
  hipMemsetAsync(gbuf, 0, (size_t)G * H * 4, stream);

  k_prep<<<144, 256, 0, stream>>>(w2_0, w2_r, w1_r, wt);
  k_build_gemm<<<NB_BUILD, 256, 0, stream>>>(src, dst, deg, slots, x, w1_0, ybuf);

  unsigned short* w2t0 = wt;
  unsigned short* w2tr = wt + 4096;
  unsigned short* w1tr = wt + 5 * 4096;

  // ping-pong: L0 ybuf->ubuf, L1 ubuf->ybuf, L2 ybuf->ubuf, L3 ubuf->ybuf
  k_agg_mlp<<<NB_TILE64, 512, 0, stream>>>(ybuf, deg, slots, b1_0,
                                           w2t0, b2_0, w1tr, ubuf);
  k_agg_mlp<<<NB_TILE64, 512, 0, stream>>>(ubuf, deg, slots, b1_r + 0 * H,
                                           w2tr + 0 * 4096, b2_r + 0 * H,
                                           w1tr + 1 * 4096, ybuf);
  k_agg_mlp<<<NB_TILE64, 512, 0, stream>>>(ybuf, deg, slots, b1_r + 1 * H,
                                           w2tr + 1 * 4096, b2_r + 1 * H,
                                           w1tr + 2 * 4096, ubuf);
  k_agg_mlp<<<NB_TILE64, 512, 0, stream>>>(ubuf, deg, slots, b1_r + 2 * H,
                                           w2tr + 2 * 4096, b2_r + 2 * H,
                                           w1tr + 3 * 4096, ybuf);
  k_agg_pool<<<NB_TILE64, 512, 0, stream>>>(ybuf, deg, slots, b1_r + 3 * H,
                                            w2tr + 3 * 4096, b2_r + 3 * H,
                                            batch, gbuf);

  k_readout<<<8, 64, 0, stream>>>(gbuf, mw1, mb1, mw2, mb2, out);
}